// Round 1
// baseline (608.563 us; speedup 1.0000x reference)
//
#include <hip/hip_runtime.h>

static constexpr int ID = 128;   // IN_DIM
static constexpr int ND = 32;    // NET_DIM

// ---- deg count: one int atomic per edge at target ----
__global__ __launch_bounds__(256) void k_count(const int* __restrict__ col, int E,
                                               unsigned* __restrict__ cnt) {
    int e = blockIdx.x * 256 + threadIdx.x;
    if (e < E) atomicAdd(&cnt[col[e]], 1u);
}

// ---- dinv = rsqrt(deg), deg includes self-loop (+1) ----
__global__ __launch_bounds__(256) void k_dinv(const unsigned* __restrict__ cnt,
                                              float* __restrict__ dinv, int n) {
    int i = blockIdx.x * 256 + threadIdx.x;
    if (i < n) dinv[i] = rsqrtf((float)(cnt[i] + 1u));
}

// ---- hs = dinv[i] * (x[i] @ W_gcn); agg init = hs (self-loop term) ----
__global__ __launch_bounds__(256) void k_gemm(const float* __restrict__ x,
                                              const float* __restrict__ W,
                                              const float* __restrict__ dinv,
                                              float* __restrict__ hs,
                                              float* __restrict__ agg, int n) {
    __shared__ float sW[ID * ND];        // 16 KB, [k][j]
    for (int i = threadIdx.x; i < ID * ND; i += 256) sW[i] = W[i];
    __syncthreads();
    int row = blockIdx.x * 256 + threadIdx.x;
    if (row >= n) return;
    float acc[ND];
#pragma unroll
    for (int j = 0; j < ND; ++j) acc[j] = 0.f;
    const float4* xr = reinterpret_cast<const float4*>(x + (size_t)row * ID);
    for (int k4 = 0; k4 < ID / 4; ++k4) {
        float4 v = xr[k4];
        const float* w0 = &sW[(k4 * 4 + 0) * ND];
        const float* w1 = &sW[(k4 * 4 + 1) * ND];
        const float* w2 = &sW[(k4 * 4 + 2) * ND];
        const float* w3 = &sW[(k4 * 4 + 3) * ND];
#pragma unroll
        for (int j = 0; j < ND; ++j)
            acc[j] += v.x * w0[j] + v.y * w1[j] + v.z * w2[j] + v.w * w3[j];
    }
    float di = dinv[row];
    float4* hp = reinterpret_cast<float4*>(hs  + (size_t)row * ND);
    float4* ap = reinterpret_cast<float4*>(agg + (size_t)row * ND);
#pragma unroll
    for (int q = 0; q < ND / 4; ++q) {
        float4 o;
        o.x = di * acc[q * 4 + 0];
        o.y = di * acc[q * 4 + 1];
        o.z = di * acc[q * 4 + 2];
        o.w = di * acc[q * 4 + 3];
        hp[q] = o;
        ap[q] = o;   // self-loop contribution
    }
}

// ---- scatter: agg[col] += hs[row], 32 lanes per edge (one channel each) ----
__global__ __launch_bounds__(256) void k_scatter(const int* __restrict__ row,
                                                 const int* __restrict__ col,
                                                 const float* __restrict__ hs,
                                                 float* __restrict__ agg, int E) {
    int tid = blockIdx.x * 256 + threadIdx.x;
    int e = tid >> 5;
    if (e >= E) return;
    int ch = tid & 31;
    int r = row[e];
    int c = col[e];
    atomicAdd(&agg[(size_t)c * ND + ch], hs[(size_t)r * ND + ch]);
}

// ---- finalize: g = relu(dinv*agg + b_gcn); out = relu(g @ W_dense + b_dense) ----
__global__ __launch_bounds__(256) void k_final(const float* __restrict__ agg,
                                               const float* __restrict__ dinv,
                                               const float* __restrict__ bg,
                                               const float* __restrict__ Wd,
                                               const float* __restrict__ bd,
                                               float* __restrict__ out, int n) {
    __shared__ float sW[ND * ND];   // 4 KB
    __shared__ float sbg[ND];
    __shared__ float sbd[ND];
    for (int i = threadIdx.x; i < ND * ND; i += 256) sW[i] = Wd[i];
    if (threadIdx.x < ND) {
        sbg[threadIdx.x] = bg[threadIdx.x];
        sbd[threadIdx.x] = bd[threadIdx.x];
    }
    __syncthreads();
    int i = blockIdx.x * 256 + threadIdx.x;
    if (i >= n) return;
    float di = dinv[i];
    const float4* ar = reinterpret_cast<const float4*>(agg + (size_t)i * ND);
    float g[ND];
#pragma unroll
    for (int q = 0; q < ND / 4; ++q) {
        float4 v = ar[q];
        g[q * 4 + 0] = fmaxf(di * v.x + sbg[q * 4 + 0], 0.f);
        g[q * 4 + 1] = fmaxf(di * v.y + sbg[q * 4 + 1], 0.f);
        g[q * 4 + 2] = fmaxf(di * v.z + sbg[q * 4 + 2], 0.f);
        g[q * 4 + 3] = fmaxf(di * v.w + sbg[q * 4 + 3], 0.f);
    }
    float acc[ND];
#pragma unroll
    for (int j2 = 0; j2 < ND; ++j2) acc[j2] = sbd[j2];
    for (int j = 0; j < ND; ++j) {
        float gj = g[j];
        const float* wrow = &sW[j * ND];
#pragma unroll
        for (int j2 = 0; j2 < ND; ++j2) acc[j2] += gj * wrow[j2];
    }
    float4* op = reinterpret_cast<float4*>(out + (size_t)i * ND);
#pragma unroll
    for (int q = 0; q < ND / 4; ++q) {
        float4 o;
        o.x = fmaxf(acc[q * 4 + 0], 0.f);
        o.y = fmaxf(acc[q * 4 + 1], 0.f);
        o.z = fmaxf(acc[q * 4 + 2], 0.f);
        o.w = fmaxf(acc[q * 4 + 3], 0.f);
        op[q] = o;
    }
}

extern "C" void kernel_launch(void* const* d_in, const int* in_sizes, int n_in,
                              void* d_out, int out_size, void* d_ws, size_t ws_size,
                              hipStream_t stream) {
    const float* x   = (const float*)d_in[0];
    const int*   ei  = (const int*)d_in[1];   // [2, E] flat: row then col
    const float* Wg  = (const float*)d_in[2];
    const float* bg  = (const float*)d_in[3];
    const float* Wd  = (const float*)d_in[4];
    const float* bd  = (const float*)d_in[5];
    float* out = (float*)d_out;

    const int n = in_sizes[0] / ID;      // 100000
    const int E = in_sizes[1] / 2;       // 3200000
    const int* erow = ei;
    const int* ecol = ei + E;

    // workspace carve-up
    float*    hs   = (float*)d_ws;                          // n*ND f32
    float*    agg  = hs  + (size_t)n * ND;                  // n*ND f32
    unsigned* cnt  = (unsigned*)(agg + (size_t)n * ND);     // n u32
    float*    dinv = (float*)(cnt + n);                     // n f32

    hipMemsetAsync(cnt, 0, (size_t)n * sizeof(unsigned), stream);
    k_count<<<(E + 255) / 256, 256, 0, stream>>>(ecol, E, cnt);
    k_dinv<<<(n + 255) / 256, 256, 0, stream>>>(cnt, dinv, n);
    k_gemm<<<(n + 255) / 256, 256, 0, stream>>>(x, Wg, dinv, hs, agg, n);
    long long sthreads = (long long)E * ND;
    k_scatter<<<(unsigned)((sthreads + 255) / 256), 256, 0, stream>>>(erow, ecol, hs, agg, E);
    k_final<<<(n + 255) / 256, 256, 0, stream>>>(agg, dinv, bg, Wd, bd, out, n);
}